// Round 1
// baseline (1617.104 us; speedup 1.0000x reference)
//
#include <hip/hip_runtime.h>
#include <math.h>

// Problem constants (fixed by reference setup)
#define S_LEN   1024
#define BATCH   2
#define DMODEL  1024
#define NHEADS  16
#define HDIM    64
#define BHEADS  32          // BATCH*NHEADS
#define LP1     4           // 1 + L layers
#define ROWS_PL 2048        // S*B rows per layer

// ---------------------------------------------------------------------------
// Tiled fp32 GEMM:  C[M,N] = A[M,1024] @ W[N,1024]^T + bias[N]
// BM=BN=64, BK=16, 256 threads, 4x4 micro-tile.
// mode 0: A rows are xs rows [l][s][b] (l = row>>11; l==0 -> x, else lo[l-1]);
//         epilogue scatters to out[((l*32 + b*16 + h)*1024 + s)*64 + e], h=blockIdx.x
// mode 1: A = x (plain row-major), epilogue writes out[m*1024 + n]
// ---------------------------------------------------------------------------
__global__ __launch_bounds__(256)
void proj_gemm(const float* __restrict__ x, const float* __restrict__ lo,
               const float* __restrict__ W, const float* __restrict__ bias,
               float* __restrict__ out, int mode)
{
    __shared__ float As[16][68];   // [k][m], padded stride 68
    __shared__ float Bs[16][68];   // [k][n]

    const int t  = threadIdx.x;
    const int tx = t & 15, ty = t >> 4;
    const int tx4 = tx * 4, ty4 = ty * 4;
    const int bx = blockIdx.x;            // n-tile (n0 = bx*64)
    const int by = blockIdx.y;            // m-tile
    const int m0 = by * 64, n0 = bx * 64;

    const float* Abase;
    int lrow = 0;
    if (mode == 0) {
        lrow = m0 >> 11;                              // uniform per block
        const float* src = (lrow == 0) ? x : (lo + (size_t)(lrow - 1) * ROWS_PL * DMODEL);
        Abase = src + (size_t)(m0 & 2047) * DMODEL;
    } else {
        Abase = x + (size_t)m0 * DMODEL;
    }

    const int arow = t >> 2;          // 0..63
    const int ac4  = (t & 3) * 4;     // 0,4,8,12

    float acc[4][4] = {};

    for (int k0 = 0; k0 < DMODEL; k0 += 16) {
        // global loads first (overlap with the barrier)
        float a4[4], b4[4];
        *(float4*)a4 = *(const float4*)(Abase + (size_t)arow * DMODEL + k0 + ac4);
        *(float4*)b4 = *(const float4*)(W + (size_t)(n0 + arow) * DMODEL + k0 + ac4);
        __syncthreads();   // previous iteration done reading LDS
        #pragma unroll
        for (int j = 0; j < 4; ++j) {
            As[ac4 + j][arow] = a4[j];
            Bs[ac4 + j][arow] = b4[j];
        }
        __syncthreads();
        #pragma unroll
        for (int kk = 0; kk < 16; ++kk) {
            float av[4], bv[4];
            *(float4*)av = *(const float4*)(&As[kk][ty4]);
            *(float4*)bv = *(const float4*)(&Bs[kk][tx4]);
            #pragma unroll
            for (int i = 0; i < 4; ++i)
                #pragma unroll
                for (int j = 0; j < 4; ++j)
                    acc[i][j] = fmaf(av[i], bv[j], acc[i][j]);
        }
    }

    float bb[4];
    *(float4*)bb = *(const float4*)(bias + n0 + tx4);

    #pragma unroll
    for (int i = 0; i < 4; ++i) {
        const int m = m0 + ty4 + i;
        float r[4];
        #pragma unroll
        for (int j = 0; j < 4; ++j) r[j] = acc[i][j] + bb[j];
        if (mode == 0) {
            const int l = m >> 11, rem = m & 2047;
            const int s = rem >> 1, b = rem & 1;
            const int h = bx;  // BN == HDIM
            const size_t dst = (((size_t)(l * 32 + b * 16 + h) * S_LEN) + s) * HDIM + tx4;
            *(float4*)(out + dst) = *(float4*)r;
        } else {
            *(float4*)(out + (size_t)m * DMODEL + n0 + tx4) = *(float4*)r;
        }
    }
}

// ---------------------------------------------------------------------------
// Flash attention over 4 layers with shared Q, per-layer softmax over keys,
// layer-weighted accumulation. One block per (bh, q-tile of 64).
// Output written to yb in [s][b][d] layout (ready for the O-projection GEMM).
// ---------------------------------------------------------------------------
__global__ __launch_bounds__(256)
void attn_kernel(const float* __restrict__ qb, const float* __restrict__ kb,
                 const float* __restrict__ vb, const float* __restrict__ lwraw,
                 float* __restrict__ yb)
{
    __shared__ float Qs[64][68];    // [e][q]
    __shared__ float KVs[64][68];   // K phase: [e][k]; V phase: [k][d]
    __shared__ float Ps[64][68];    // [k][q]

    const int t  = threadIdx.x;
    const int tx = t & 15, ty = t >> 4;
    const int tx4 = tx * 4, ty4 = ty * 4;
    const int qt = blockIdx.x;          // 0..15
    const int bh = blockIdx.y;          // 0..31
    const int qs0 = qt * 64;

    // layer-weight softmax (computed redundantly per thread; 4 elements)
    float w[LP1];
    {
        float wm = -3.0e38f;
        #pragma unroll
        for (int l = 0; l < LP1; ++l) { w[l] = lwraw[l]; wm = fmaxf(wm, w[l]); }
        float ws = 0.f;
        #pragma unroll
        for (int l = 0; l < LP1; ++l) { w[l] = __expf(w[l] - wm); ws += w[l]; }
        const float inv = 1.0f / ws;
        #pragma unroll
        for (int l = 0; l < LP1; ++l) w[l] *= inv;
    }

    // load + transpose Q tile
    {
        const float* qsrc = qb + ((size_t)bh * S_LEN + qs0) * HDIM;
        #pragma unroll
        for (int c = 0; c < 4; ++c) {
            const int fid = c * 256 + t;
            const int row = fid >> 4, e4 = (fid & 15) * 4;
            float v[4];
            *(float4*)v = *(const float4*)(qsrc + fid * 4);
            #pragma unroll
            for (int j = 0; j < 4; ++j) Qs[e4 + j][row] = v[j];
        }
    }

    float fin[4][4] = {};
    const float SCL = 0.125f * 1.44269504088896340736f;  // hd^-0.5 * log2(e)

    for (int l = 0; l < LP1; ++l) {
        const float* kbase = kb + ((size_t)l * BHEADS + bh) * S_LEN * HDIM;
        const float* vbase = vb + ((size_t)l * BHEADS + bh) * S_LEN * HDIM;

        float m_i[4], ls_i[4];
        #pragma unroll
        for (int i = 0; i < 4; ++i) { m_i[i] = -3.0e38f; ls_i[i] = 0.f; }
        float o[4][4] = {};

        for (int kt = 0; kt < 16; ++kt) {
            // K tile -> regs
            float kr[4][4];
            {
                const float* ksrc = kbase + (size_t)kt * 64 * HDIM;
                #pragma unroll
                for (int c = 0; c < 4; ++c)
                    *(float4*)kr[c] = *(const float4*)(ksrc + (c * 256 + t) * 4);
            }
            __syncthreads();   // KVs/Ps free from previous iteration
            #pragma unroll
            for (int c = 0; c < 4; ++c) {
                const int fid = c * 256 + t;
                const int row = fid >> 4, e4 = (fid & 15) * 4;
                #pragma unroll
                for (int j = 0; j < 4; ++j) KVs[e4 + j][row] = kr[c][j];
            }
            __syncthreads();

            // S = Q K^T * scale (log2 domain)
            float s[4][4] = {};
            #pragma unroll
            for (int e = 0; e < 64; ++e) {
                float qa[4], ka[4];
                *(float4*)qa = *(const float4*)(&Qs[e][ty4]);
                *(float4*)ka = *(const float4*)(&KVs[e][tx4]);
                #pragma unroll
                for (int i = 0; i < 4; ++i)
                    #pragma unroll
                    for (int j = 0; j < 4; ++j)
                        s[i][j] = fmaf(qa[i], ka[j], s[i][j]);
            }

            // V tile -> regs (overlap with barrier)
            float vr[4][4];
            {
                const float* vsrc = vbase + (size_t)kt * 64 * HDIM;
                #pragma unroll
                for (int c = 0; c < 4; ++c)
                    *(float4*)vr[c] = *(const float4*)(vsrc + (c * 256 + t) * 4);
            }
            __syncthreads();   // everyone done reading K from KVs

            // V natural layout [k][d]
            #pragma unroll
            for (int c = 0; c < 4; ++c) {
                const int fid = c * 256 + t;
                *(float4*)(&KVs[fid >> 4][(fid & 15) * 4]) = *(float4*)vr[c];
            }

            // online softmax (rows q=ty4+i owned by 16 consecutive lanes)
            #pragma unroll
            for (int i = 0; i < 4; ++i) {
                float mx = fmaxf(fmaxf(s[i][0] * SCL, s[i][1] * SCL),
                                 fmaxf(s[i][2] * SCL, s[i][3] * SCL));
                #pragma unroll
                for (int off = 1; off < 16; off <<= 1)
                    mx = fmaxf(mx, __shfl_xor(mx, off, 16));
                const float mnew = fmaxf(m_i[i], mx);
                const float alpha = exp2f(m_i[i] - mnew);
                m_i[i] = mnew;
                float psum = 0.f;
                #pragma unroll
                for (int j = 0; j < 4; ++j) {
                    const float p = exp2f(s[i][j] * SCL - mnew);
                    s[i][j] = p;
                    psum += p;
                }
                #pragma unroll
                for (int off = 1; off < 16; off <<= 1)
                    psum += __shfl_xor(psum, off, 16);
                ls_i[i] = ls_i[i] * alpha + psum;
                #pragma unroll
                for (int j = 0; j < 4; ++j) o[i][j] *= alpha;
            }
            // write P transposed: Ps[k][q], float4 along q
            #pragma unroll
            for (int j = 0; j < 4; ++j) {
                float pv[4] = { s[0][j], s[1][j], s[2][j], s[3][j] };
                *(float4*)(&Ps[tx4 + j][ty4]) = *(float4*)pv;
            }
            __syncthreads();   // Ps + V ready

            // O += P V
            #pragma unroll
            for (int kk = 0; kk < 64; ++kk) {
                float pa[4], vv[4];
                *(float4*)pa = *(const float4*)(&Ps[kk][ty4]);
                *(float4*)vv = *(const float4*)(&KVs[kk][tx4]);
                #pragma unroll
                for (int i = 0; i < 4; ++i)
                    #pragma unroll
                    for (int j = 0; j < 4; ++j)
                        o[i][j] = fmaf(pa[i], vv[j], o[i][j]);
            }
        }

        // layer epilogue: fin += w[l] * O / lsum
        #pragma unroll
        for (int i = 0; i < 4; ++i) {
            const float sc = w[l] / ls_i[i];
            #pragma unroll
            for (int j = 0; j < 4; ++j) fin[i][j] = fmaf(o[i][j], sc, fin[i][j]);
        }
        __syncthreads();  // KVs/Ps consumed before next layer overwrites
    }

    // write combined in [s][b][d] layout
    const int b = bh >> 4, h = bh & 15;
    #pragma unroll
    for (int i = 0; i < 4; ++i) {
        const int s_idx = qs0 + ty4 + i;
        const size_t dst = ((size_t)s_idx * BATCH + b) * DMODEL + h * HDIM + tx4;
        *(float4*)(yb + dst) = *(float4*)fin[i];
    }
}

// ---------------------------------------------------------------------------
extern "C" void kernel_launch(void* const* d_in, const int* in_sizes, int n_in,
                              void* d_out, int out_size, void* d_ws, size_t ws_size,
                              hipStream_t stream) {
    const float* x  = (const float*)d_in[0];
    const float* lo = (const float*)d_in[1];
    const float* Wq = (const float*)d_in[2];
    const float* bq = (const float*)d_in[3];
    const float* Wk = (const float*)d_in[4];
    const float* bk = (const float*)d_in[5];
    const float* Wv = (const float*)d_in[6];
    const float* bv = (const float*)d_in[7];
    const float* Wo = (const float*)d_in[8];
    const float* bo = (const float*)d_in[9];
    const float* lw = (const float*)d_in[10];
    float* out = (float*)d_out;

    float* ws = (float*)d_ws;
    float* qbuf = ws;                         //  2,097,152 floats
    float* kbuf = qbuf + 2097152;             //  8,388,608
    float* vbuf = kbuf + 8388608;             //  8,388,608
    float* ybuf = vbuf + 8388608;             //  2,097,152
    // total 20,971,520 floats = 80 MB

    dim3 blk(256);
    // Q projection: M = 2048
    proj_gemm<<<dim3(16, 32), blk, 0, stream>>>(x, lo, Wq, bq, qbuf, 0);
    // K projection: M = 8192 (x ++ layer_outputs)
    proj_gemm<<<dim3(16, 128), blk, 0, stream>>>(x, lo, Wk, bk, kbuf, 0);
    // V projection
    proj_gemm<<<dim3(16, 128), blk, 0, stream>>>(x, lo, Wv, bv, vbuf, 0);
    // attention
    attn_kernel<<<dim3(16, 32), blk, 0, stream>>>(qbuf, kbuf, vbuf, lw, ybuf);
    // output projection (plain row-major in/out)
    proj_gemm<<<dim3(16, 32), blk, 0, stream>>>(ybuf, nullptr, Wo, bo, out, 1);
}

// Round 2
// 1123.601 us; speedup vs baseline: 1.4392x; 1.4392x over previous
//
#include <hip/hip_runtime.h>
#include <math.h>

// Problem constants (fixed by reference setup)
#define S_LEN   1024
#define BATCH   2
#define DMODEL  1024
#define NHEADS  16
#define HDIM    64
#define BHEADS  32          // BATCH*NHEADS
#define LP1     4           // 1 + L layers
#define ROWS_PL 2048        // S*B rows per layer

typedef __attribute__((ext_vector_type(8))) short bf16x8;   // 8 bf16 = 4 VGPRs
typedef __attribute__((ext_vector_type(4))) float f32x4;    // MFMA acc

__device__ inline ushort bf16_rne(float a) {
    unsigned u = __float_as_uint(a);
    return (ushort)((u + 0x7FFFu + ((u >> 16) & 1u)) >> 16);
}
__device__ inline float bf16_up(ushort h) { return __uint_as_float(((unsigned)h) << 16); }
__device__ inline void split_bf16(float a, ushort &hi, ushort &lo) {
    hi = bf16_rne(a);
    lo = bf16_rne(a - bf16_up(hi));
}

// ---------------------------------------------------------------------------
// Split-bf16 MFMA GEMM: C[M,N] = A[M,1024] @ W[N,1024]^T + bias[N]
// Emulated fp32 via hi/lo bf16 split, 3 MFMAs (hh, hl, lh) per tile-pair.
// BM = WM*MI*16, BN = WN*NJ*16, BK = 32, 256 threads (4 waves, WM x WN grid).
// LDS layout [row][quad][8] bf16: ds_write sequential 16B, frag reads 2-way
// (free). A-frag for mfma_16x16x32: lane holds A[m=lane&15][k=(lane>>4)*8+j].
// C/D: col = lane&15, row = (lane>>4)*4 + reg.
// mode 0: A rows span [x ; layer_outputs] (l = row>>11), epilogue scatters to
//         out[((l*32 + b*16 + h)*1024 + s)*64 + e]
// mode 1: plain row-major out[m*1024 + n]
// ---------------------------------------------------------------------------
template<int WM, int WN, int MI, int NJ>
__global__ __launch_bounds__(256)
void proj_mfma(const float* __restrict__ x, const float* __restrict__ lo,
               const float* __restrict__ W, const float* __restrict__ bias,
               float* __restrict__ out, const int mode)
{
    constexpr int BM = WM * MI * 16;
    constexpr int BN = WN * NJ * 16;
    constexpr int AT = (BM * 4) / 256;   // A staging tasks per thread
    constexpr int BT = (BN * 4) / 256;

    __shared__ ushort Ah[BM][4][8], Al[BM][4][8];
    __shared__ ushort Bh[BN][4][8], Bl[BN][4][8];

    const int t  = threadIdx.x;
    const int m0 = blockIdx.y * BM, n0 = blockIdx.x * BN;

    const float* Abase;
    if (mode == 0) {
        const int l = m0 >> 11;                       // uniform per block
        const float* src = (l == 0) ? x : (lo + (size_t)(l - 1) * ROWS_PL * DMODEL);
        Abase = src + (size_t)(m0 & 2047) * DMODEL;
    } else {
        Abase = x + (size_t)m0 * DMODEL;
    }
    const float* Bbase = W + (size_t)n0 * DMODEL;

    const int wave = t >> 6, lane = t & 63;
    const int quad = lane >> 4, r = lane & 15;
    const int wm = wave % WM, wn = wave / WM;
    const int mBase = wm * MI * 16, nBase = wn * NJ * 16;

    f32x4 acc[MI][NJ];
    #pragma unroll
    for (int i = 0; i < MI; ++i)
        #pragma unroll
        for (int j = 0; j < NJ; ++j) acc[i][j] = (f32x4){0.f, 0.f, 0.f, 0.f};

    for (int k0 = 0; k0 < DMODEL; k0 += 32) {
        // ---- global fp32 loads into regs (before barrier, hides latency) ----
        float ar[AT][8], br[BT][8];
        #pragma unroll
        for (int c = 0; c < AT; ++c) {
            const int tau = c * 256 + t;
            const float* p = Abase + (size_t)(tau >> 2) * DMODEL + k0 + (tau & 3) * 8;
            *(float4*)&ar[c][0] = *(const float4*)p;
            *(float4*)&ar[c][4] = *(const float4*)(p + 4);
        }
        #pragma unroll
        for (int c = 0; c < BT; ++c) {
            const int tau = c * 256 + t;
            const float* p = Bbase + (size_t)(tau >> 2) * DMODEL + k0 + (tau & 3) * 8;
            *(float4*)&br[c][0] = *(const float4*)p;
            *(float4*)&br[c][4] = *(const float4*)(p + 4);
        }
        __syncthreads();   // previous iteration's frag reads done
        // ---- convert to hi/lo bf16, store to LDS ----
        #pragma unroll
        for (int c = 0; c < AT; ++c) {
            const int tau = c * 256 + t;
            const int row = tau >> 2, q = tau & 3;
            ushort hv[8], lv[8];
            #pragma unroll
            for (int j = 0; j < 8; ++j) split_bf16(ar[c][j], hv[j], lv[j]);
            *(uint4*)&Ah[row][q][0] = *(uint4*)hv;
            *(uint4*)&Al[row][q][0] = *(uint4*)lv;
        }
        #pragma unroll
        for (int c = 0; c < BT; ++c) {
            const int tau = c * 256 + t;
            const int row = tau >> 2, q = tau & 3;
            ushort hv[8], lv[8];
            #pragma unroll
            for (int j = 0; j < 8; ++j) split_bf16(br[c][j], hv[j], lv[j]);
            *(uint4*)&Bh[row][q][0] = *(uint4*)hv;
            *(uint4*)&Bl[row][q][0] = *(uint4*)lv;
        }
        __syncthreads();
        // ---- fragments + MFMA ----
        bf16x8 fa_h[MI], fa_l[MI], fb_h[NJ], fb_l[NJ];
        #pragma unroll
        for (int i = 0; i < MI; ++i) {
            fa_h[i] = *(const bf16x8*)&Ah[mBase + i * 16 + r][quad][0];
            fa_l[i] = *(const bf16x8*)&Al[mBase + i * 16 + r][quad][0];
        }
        #pragma unroll
        for (int j = 0; j < NJ; ++j) {
            fb_h[j] = *(const bf16x8*)&Bh[nBase + j * 16 + r][quad][0];
            fb_l[j] = *(const bf16x8*)&Bl[nBase + j * 16 + r][quad][0];
        }
        #pragma unroll
        for (int i = 0; i < MI; ++i)
            #pragma unroll
            for (int j = 0; j < NJ; ++j) {
                acc[i][j] = __builtin_amdgcn_mfma_f32_16x16x32_bf16(fa_h[i], fb_h[j], acc[i][j], 0, 0, 0);
                acc[i][j] = __builtin_amdgcn_mfma_f32_16x16x32_bf16(fa_h[i], fb_l[j], acc[i][j], 0, 0, 0);
                acc[i][j] = __builtin_amdgcn_mfma_f32_16x16x32_bf16(fa_l[i], fb_h[j], acc[i][j], 0, 0, 0);
            }
    }

    // ---- epilogue: bias + scatter ----
    const int cn = lane & 15;
    #pragma unroll
    for (int j = 0; j < NJ; ++j) {
        const int n = n0 + nBase + j * 16 + cn;
        const float bv = bias[n];
        #pragma unroll
        for (int i = 0; i < MI; ++i) {
            const int mrow = m0 + mBase + i * 16 + quad * 4;
            #pragma unroll
            for (int g = 0; g < 4; ++g) {
                const float val = acc[i][j][g] + bv;
                const int m = mrow + g;
                if (mode == 0) {
                    const int l = m >> 11, rem = m & 2047;
                    const int s = rem >> 1, b = rem & 1;
                    const int h = n >> 6, e = n & 63;
                    out[(((size_t)(l * 32 + b * 16 + h) * S_LEN) + s) * HDIM + e] = val;
                } else {
                    out[(size_t)m * DMODEL + n] = val;
                }
            }
        }
    }
}

// ---------------------------------------------------------------------------
// Flash attention over 4 layers, fp32 vector ALU. q-tile = 32 (grid 32x32 =
// 1024 blocks = 4/CU; LDS 35.8 KB). Per-thread micro-tile 2x4.
// ---------------------------------------------------------------------------
__global__ __launch_bounds__(256)
void attn_kernel(const float* __restrict__ qb, const float* __restrict__ kb,
                 const float* __restrict__ vb, const float* __restrict__ lwraw,
                 float* __restrict__ yb)
{
    __shared__ float Qs[64][36];    // [e][q], q-tile 32 (+4 pad)
    __shared__ float KVs[64][68];   // K phase: [e][k]; V phase: [k][d]
    __shared__ float Ps[64][36];    // [k][q]

    const int t   = threadIdx.x;
    const int tx  = t & 15, ty = t >> 4;
    const int tx4 = tx * 4, ty2 = ty * 2;
    const int qt  = blockIdx.x;          // 0..31
    const int bh  = blockIdx.y;          // 0..31
    const int qs0 = qt * 32;

    // layer-weight softmax (redundant per thread, 4 elems)
    float w[LP1];
    {
        float wm = -3.0e38f;
        #pragma unroll
        for (int l = 0; l < LP1; ++l) { w[l] = lwraw[l]; wm = fmaxf(wm, w[l]); }
        float ws = 0.f;
        #pragma unroll
        for (int l = 0; l < LP1; ++l) { w[l] = __expf(w[l] - wm); ws += w[l]; }
        const float inv = 1.0f / ws;
        #pragma unroll
        for (int l = 0; l < LP1; ++l) w[l] *= inv;
    }

    // load + transpose Q tile: 32 rows x 64 e
    {
        const float* qsrc = qb + ((size_t)bh * S_LEN + qs0) * HDIM;
        #pragma unroll
        for (int c = 0; c < 2; ++c) {
            const int fid = c * 256 + t;
            const int row = fid >> 4, e4 = (fid & 15) * 4;
            float v[4];
            *(float4*)v = *(const float4*)(qsrc + fid * 4);
            #pragma unroll
            for (int j = 0; j < 4; ++j) Qs[e4 + j][row] = v[j];
        }
    }

    float fin[2][4] = {};
    const float SCL = 0.125f * 1.44269504088896340736f;  // hd^-0.5 * log2(e)

    for (int l = 0; l < LP1; ++l) {
        const float* kbase = kb + ((size_t)l * BHEADS + bh) * S_LEN * HDIM;
        const float* vbase = vb + ((size_t)l * BHEADS + bh) * S_LEN * HDIM;

        float m_i[2], ls_i[2];
        #pragma unroll
        for (int i = 0; i < 2; ++i) { m_i[i] = -3.0e38f; ls_i[i] = 0.f; }
        float o[2][4] = {};

        for (int kt = 0; kt < 16; ++kt) {
            // K tile -> regs
            float kr[4][4];
            {
                const float* ksrc = kbase + (size_t)kt * 64 * HDIM;
                #pragma unroll
                for (int c = 0; c < 4; ++c)
                    *(float4*)kr[c] = *(const float4*)(ksrc + (c * 256 + t) * 4);
            }
            __syncthreads();   // KVs/Ps free from previous iteration
            #pragma unroll
            for (int c = 0; c < 4; ++c) {
                const int fid = c * 256 + t;
                const int row = fid >> 4, e4 = (fid & 15) * 4;
                #pragma unroll
                for (int j = 0; j < 4; ++j) KVs[e4 + j][row] = kr[c][j];
            }
            __syncthreads();

            // S = Q K^T (pre-scale)
            float s[2][4] = {};
            #pragma unroll
            for (int e = 0; e < 64; ++e) {
                float qa[2], ka[4];
                *(float2*)qa = *(const float2*)(&Qs[e][ty2]);
                *(float4*)ka = *(const float4*)(&KVs[e][tx4]);
                #pragma unroll
                for (int i = 0; i < 2; ++i)
                    #pragma unroll
                    for (int j = 0; j < 4; ++j)
                        s[i][j] = fmaf(qa[i], ka[j], s[i][j]);
            }

            // V tile -> regs (overlap with barrier)
            float vr[4][4];
            {
                const float* vsrc = vbase + (size_t)kt * 64 * HDIM;
                #pragma unroll
                for (int c = 0; c < 4; ++c)
                    *(float4*)vr[c] = *(const float4*)(vsrc + (c * 256 + t) * 4);
            }
            __syncthreads();   // all done reading K from KVs

            // V natural layout [k][d]
            #pragma unroll
            for (int c = 0; c < 4; ++c) {
                const int fid = c * 256 + t;
                *(float4*)(&KVs[fid >> 4][(fid & 15) * 4]) = *(float4*)vr[c];
            }

            // online softmax, rows q = ty2 + i (owned by the 16 lanes of ty)
            #pragma unroll
            for (int i = 0; i < 2; ++i) {
                float mx = fmaxf(fmaxf(s[i][0] * SCL, s[i][1] * SCL),
                                 fmaxf(s[i][2] * SCL, s[i][3] * SCL));
                #pragma unroll
                for (int off = 1; off < 16; off <<= 1)
                    mx = fmaxf(mx, __shfl_xor(mx, off, 16));
                const float mnew = fmaxf(m_i[i], mx);
                const float alpha = exp2f(m_i[i] - mnew);
                m_i[i] = mnew;
                float psum = 0.f;
                #pragma unroll
                for (int j = 0; j < 4; ++j) {
                    const float p = exp2f(s[i][j] * SCL - mnew);
                    s[i][j] = p;
                    psum += p;
                }
                #pragma unroll
                for (int off = 1; off < 16; off <<= 1)
                    psum += __shfl_xor(psum, off, 16);
                ls_i[i] = ls_i[i] * alpha + psum;
                #pragma unroll
                for (int j = 0; j < 4; ++j) o[i][j] *= alpha;
            }
            // write P transposed: Ps[k][q], float2 along q
            #pragma unroll
            for (int j = 0; j < 4; ++j) {
                float pv[2] = { s[0][j], s[1][j] };
                *(float2*)(&Ps[tx4 + j][ty2]) = *(float2*)pv;
            }
            __syncthreads();   // Ps + V ready

            // O += P V
            #pragma unroll
            for (int kk = 0; kk < 64; ++kk) {
                float pa[2], vv[4];
                *(float2*)pa = *(const float2*)(&Ps[kk][ty2]);
                *(float4*)vv = *(const float4*)(&KVs[kk][tx4]);
                #pragma unroll
                for (int i = 0; i < 2; ++i)
                    #pragma unroll
                    for (int j = 0; j < 4; ++j)
                        o[i][j] = fmaf(pa[i], vv[j], o[i][j]);
            }
        }

        // layer epilogue: fin += w[l] * O / lsum
        #pragma unroll
        for (int i = 0; i < 2; ++i) {
            const float sc = w[l] / ls_i[i];
            #pragma unroll
            for (int j = 0; j < 4; ++j) fin[i][j] = fmaf(o[i][j], sc, fin[i][j]);
        }
        __syncthreads();  // KVs/Ps consumed before next layer overwrites
    }

    // write combined in [s][b][d] layout
    const int b = bh >> 4, h = bh & 15;
    #pragma unroll
    for (int i = 0; i < 2; ++i) {
        const int s_idx = qs0 + ty2 + i;
        const size_t dst = ((size_t)s_idx * BATCH + b) * DMODEL + h * HDIM + tx4;
        *(float4*)(yb + dst) = *(float4*)fin[i];
    }
}

// ---------------------------------------------------------------------------
extern "C" void kernel_launch(void* const* d_in, const int* in_sizes, int n_in,
                              void* d_out, int out_size, void* d_ws, size_t ws_size,
                              hipStream_t stream) {
    const float* x  = (const float*)d_in[0];
    const float* lo = (const float*)d_in[1];
    const float* Wq = (const float*)d_in[2];
    const float* bq = (const float*)d_in[3];
    const float* Wk = (const float*)d_in[4];
    const float* bk = (const float*)d_in[5];
    const float* Wv = (const float*)d_in[6];
    const float* bv = (const float*)d_in[7];
    const float* Wo = (const float*)d_in[8];
    const float* bo = (const float*)d_in[9];
    const float* lw = (const float*)d_in[10];
    float* out = (float*)d_out;

    float* ws = (float*)d_ws;
    float* qbuf = ws;                         //  2,097,152 floats
    float* kbuf = qbuf + 2097152;             //  8,388,608
    float* vbuf = kbuf + 8388608;             //  8,388,608
    float* ybuf = vbuf + 8388608;             //  2,097,152

    dim3 blk(256);
    // Q projection: M=2048 -> BM=64 tiles, grid (8,32)=256 blocks
    proj_mfma<1, 4, 4, 2><<<dim3(8, 32), blk, 0, stream>>>(x, lo, Wq, bq, qbuf, 0);
    // K/V projections: M=8192 -> BM=128, grid (8,64)=512 blocks
    proj_mfma<2, 2, 4, 4><<<dim3(8, 64), blk, 0, stream>>>(x, lo, Wk, bk, kbuf, 0);
    proj_mfma<2, 2, 4, 4><<<dim3(8, 64), blk, 0, stream>>>(x, lo, Wv, bv, vbuf, 0);
    // attention: q-tile 32, grid (32,32)=1024 blocks
    attn_kernel<<<dim3(32, 32), blk, 0, stream>>>(qbuf, kbuf, vbuf, lw, ybuf);
    // output projection
    proj_mfma<1, 4, 4, 2><<<dim3(8, 32), blk, 0, stream>>>(ybuf, nullptr, Wo, bo, out, 1);
}

// Round 3
// 653.281 us; speedup vs baseline: 2.4754x; 1.7199x over previous
//
#include <hip/hip_runtime.h>
#include <math.h>

// Problem constants (fixed by reference setup)
#define S_LEN   1024
#define BATCH   2
#define DMODEL  1024
#define NHEADS  16
#define HDIM    64
#define BHEADS  32          // BATCH*NHEADS
#define LP1     4           // 1 + L layers
#define ROWS_PL 2048        // S*B rows per layer

typedef __attribute__((ext_vector_type(8)))  short bf16x8;   // 8 bf16 = 4 VGPRs
typedef __attribute__((ext_vector_type(4)))  float f32x4;
typedef __attribute__((ext_vector_type(16))) float f32x16;

__device__ inline ushort bf16_rne(float a) {
    unsigned u = __float_as_uint(a);
    return (ushort)((u + 0x7FFFu + ((u >> 16) & 1u)) >> 16);
}
__device__ inline float bf16_up(ushort h) { return __uint_as_float(((unsigned)h) << 16); }
__device__ inline void split_bf16(float a, ushort &hi, ushort &lo) {
    hi = bf16_rne(a);
    lo = bf16_rne(a - bf16_up(hi));
}

// ---------------------------------------------------------------------------
// Split-bf16 MFMA GEMM: C[M,N] = A[M,1024] @ W[N,1024]^T + bias[N]
// (unchanged structure from R2 — verified). Epilogue modes:
//   0: fp32 scatter to [l*32+b*16+h][s][e]   (Q; l==0 only)
//   1: fp32 row-major out[m][n]              (O-proj)
//   2: split bf16 hi/lo to [l*32+b*16+h][s][e]        (K)
//   3: split bf16 hi/lo transposed to [l*32+b*16+h][e][s]  (V^T)
// ---------------------------------------------------------------------------
template<int WM, int WN, int MI, int NJ>
__global__ __launch_bounds__(256)
void proj_mfma(const float* __restrict__ x, const float* __restrict__ lo,
               const float* __restrict__ W, const float* __restrict__ bias,
               float* __restrict__ outf, ushort* __restrict__ outh,
               ushort* __restrict__ outl, const int mode)
{
    constexpr int BM = WM * MI * 16;
    constexpr int BN = WN * NJ * 16;
    constexpr int AT = (BM * 4) / 256;
    constexpr int BT = (BN * 4) / 256;

    __shared__ ushort Ah[BM][4][8], Al[BM][4][8];
    __shared__ ushort Bh[BN][4][8], Bl[BN][4][8];

    const int t  = threadIdx.x;
    const int m0 = blockIdx.y * BM, n0 = blockIdx.x * BN;

    const float* Abase;
    if (mode != 1) {
        const int l = m0 >> 11;
        const float* src = (l == 0) ? x : (lo + (size_t)(l - 1) * ROWS_PL * DMODEL);
        Abase = src + (size_t)(m0 & 2047) * DMODEL;
    } else {
        Abase = x + (size_t)m0 * DMODEL;
    }
    const float* Bbase = W + (size_t)n0 * DMODEL;

    const int wave = t >> 6, lane = t & 63;
    const int quad = lane >> 4, r = lane & 15;
    const int wm = wave % WM, wn = wave / WM;
    const int mBase = wm * MI * 16, nBase = wn * NJ * 16;

    f32x4 acc[MI][NJ];
    #pragma unroll
    for (int i = 0; i < MI; ++i)
        #pragma unroll
        for (int j = 0; j < NJ; ++j) acc[i][j] = (f32x4){0.f, 0.f, 0.f, 0.f};

    for (int k0 = 0; k0 < DMODEL; k0 += 32) {
        float ar[AT][8], br[BT][8];
        #pragma unroll
        for (int c = 0; c < AT; ++c) {
            const int tau = c * 256 + t;
            const float* p = Abase + (size_t)(tau >> 2) * DMODEL + k0 + (tau & 3) * 8;
            *(float4*)&ar[c][0] = *(const float4*)p;
            *(float4*)&ar[c][4] = *(const float4*)(p + 4);
        }
        #pragma unroll
        for (int c = 0; c < BT; ++c) {
            const int tau = c * 256 + t;
            const float* p = Bbase + (size_t)(tau >> 2) * DMODEL + k0 + (tau & 3) * 8;
            *(float4*)&br[c][0] = *(const float4*)p;
            *(float4*)&br[c][4] = *(const float4*)(p + 4);
        }
        __syncthreads();
        #pragma unroll
        for (int c = 0; c < AT; ++c) {
            const int tau = c * 256 + t;
            const int row = tau >> 2, q = tau & 3;
            ushort hv[8], lv[8];
            #pragma unroll
            for (int j = 0; j < 8; ++j) split_bf16(ar[c][j], hv[j], lv[j]);
            *(uint4*)&Ah[row][q][0] = *(uint4*)hv;
            *(uint4*)&Al[row][q][0] = *(uint4*)lv;
        }
        #pragma unroll
        for (int c = 0; c < BT; ++c) {
            const int tau = c * 256 + t;
            const int row = tau >> 2, q = tau & 3;
            ushort hv[8], lv[8];
            #pragma unroll
            for (int j = 0; j < 8; ++j) split_bf16(br[c][j], hv[j], lv[j]);
            *(uint4*)&Bh[row][q][0] = *(uint4*)hv;
            *(uint4*)&Bl[row][q][0] = *(uint4*)lv;
        }
        __syncthreads();
        bf16x8 fa_h[MI], fa_l[MI], fb_h[NJ], fb_l[NJ];
        #pragma unroll
        for (int i = 0; i < MI; ++i) {
            fa_h[i] = *(const bf16x8*)&Ah[mBase + i * 16 + r][quad][0];
            fa_l[i] = *(const bf16x8*)&Al[mBase + i * 16 + r][quad][0];
        }
        #pragma unroll
        for (int j = 0; j < NJ; ++j) {
            fb_h[j] = *(const bf16x8*)&Bh[nBase + j * 16 + r][quad][0];
            fb_l[j] = *(const bf16x8*)&Bl[nBase + j * 16 + r][quad][0];
        }
        #pragma unroll
        for (int i = 0; i < MI; ++i)
            #pragma unroll
            for (int j = 0; j < NJ; ++j) {
                acc[i][j] = __builtin_amdgcn_mfma_f32_16x16x32_bf16(fa_h[i], fb_h[j], acc[i][j], 0, 0, 0);
                acc[i][j] = __builtin_amdgcn_mfma_f32_16x16x32_bf16(fa_h[i], fb_l[j], acc[i][j], 0, 0, 0);
                acc[i][j] = __builtin_amdgcn_mfma_f32_16x16x32_bf16(fa_l[i], fb_h[j], acc[i][j], 0, 0, 0);
            }
    }

    const int cn = lane & 15;
    #pragma unroll
    for (int j = 0; j < NJ; ++j) {
        const int n = n0 + nBase + j * 16 + cn;
        const float bv = bias[n];
        #pragma unroll
        for (int i = 0; i < MI; ++i) {
            const int mrow = m0 + mBase + i * 16 + quad * 4;
            #pragma unroll
            for (int g = 0; g < 4; ++g) {
                const float val = acc[i][j][g] + bv;
                const int m = mrow + g;
                if (mode == 1) {
                    outf[(size_t)m * DMODEL + n] = val;
                } else {
                    const int l = m >> 11, rem = m & 2047;
                    const int s = rem >> 1, b = rem & 1;
                    const int h = n >> 6, e = n & 63;
                    const int bh = l * 32 + b * 16 + h;
                    if (mode == 0) {
                        outf[(((size_t)bh * S_LEN) + s) * HDIM + e] = val;
                    } else {
                        ushort hi, lov; split_bf16(val, hi, lov);
                        size_t idx;
                        if (mode == 2) idx = (((size_t)bh * S_LEN) + s) * HDIM + e;
                        else           idx = (((size_t)bh * HDIM) + e) * S_LEN + s;
                        outh[idx] = hi; outl[idx] = lov;
                    }
                }
            }
        }
    }
}

// ---------------------------------------------------------------------------
// MFMA flash attention, one wave (64 thr) per (q-tile 32, bh, layer).
// No barriers. mfma_f32_32x32x16_bf16 throughout, split-bf16 precision.
//   A-frag: lane holds A[m=lane&31][k=(lane>>5)*8+j]
//   C/D:    col=lane&31, row=(reg&3)+8*(reg>>2)+4*(lane>>5)
// K frags read directly from global (pre-split planes, L2/L3-resident).
// P goes C-layout -> A-layout via a per-wave 8KB swizzled LDS tile.
// No-max softmax: P = exp2(s*SCL) (scores bounded << exp2 range), linear
// row-sum accumulate, one shuffle-reduce at the end, atomicAdd epilogue.
// ---------------------------------------------------------------------------
__global__ __launch_bounds__(64, 2)
void attn_mfma(const float* __restrict__ qb,
               const ushort* __restrict__ kh, const ushort* __restrict__ kl,
               const ushort* __restrict__ vth, const ushort* __restrict__ vtl,
               const float* __restrict__ lwraw, float* __restrict__ yb)
{
    __shared__ uint Ps[64 * 32];   // (hi | lo<<16) pairs, [k][swizzled q]

    const int lane = threadIdx.x;
    const int half = lane >> 5, lid = lane & 31;
    const int qt = blockIdx.x, bh = blockIdx.y, l = blockIdx.z;
    const int qs0 = qt * 32;
    const float SCL = 0.125f * 1.44269504088896340736f;

    // layer weight softmax over the first LP1 entries; keep w[l]
    float wl;
    {
        float v[LP1], wm = -3.0e38f;
        #pragma unroll
        for (int i = 0; i < LP1; ++i) { v[i] = lwraw[i]; wm = fmaxf(wm, v[i]); }
        float ws = 0.f;
        #pragma unroll
        for (int i = 0; i < LP1; ++i) { v[i] = __expf(v[i] - wm); ws += v[i]; }
        wl = v[l] / ws;
    }

    // Q A-frags (fp32 global -> split bf16 in regs), once per block
    bf16x8 qh[4], ql[4];
    {
        const float* qsrc = qb + (((size_t)bh * S_LEN) + qs0 + lid) * HDIM + half * 8;
        #pragma unroll
        for (int es = 0; es < 4; ++es) {
            float qv[8];
            *(float4*)&qv[0] = *(const float4*)(qsrc + es * 16);
            *(float4*)&qv[4] = *(const float4*)(qsrc + es * 16 + 4);
            ushort hv[8], lv[8];
            #pragma unroll
            for (int j = 0; j < 8; ++j) split_bf16(qv[j], hv[j], lv[j]);
            qh[es] = *(bf16x8*)hv;
            ql[es] = *(bf16x8*)lv;
        }
    }

    f32x16 o[2];
    #pragma unroll
    for (int d = 0; d < 2; ++d)
        #pragma unroll
        for (int i = 0; i < 16; ++i) o[d][i] = 0.f;
    float ls[16];
    #pragma unroll
    for (int i = 0; i < 16; ++i) ls[i] = 0.f;

    const size_t kvbase = (size_t)(l * BHEADS + bh) * S_LEN * HDIM;

    for (int kt = 0; kt < 16; ++kt) {
        // ---- S = Q K^T over a 64-key tile (2 kcols of 32) ----
        f32x16 sa[2];
        #pragma unroll
        for (int c = 0; c < 2; ++c)
            #pragma unroll
            for (int i = 0; i < 16; ++i) sa[c][i] = 0.f;

        #pragma unroll
        for (int es = 0; es < 4; ++es)
            #pragma unroll
            for (int kc = 0; kc < 2; ++kc) {
                const size_t off = kvbase + (size_t)(kt * 64 + kc * 32 + lid) * HDIM
                                 + es * 16 + half * 8;
                const bf16x8 kbh = *(const bf16x8*)(kh + off);
                const bf16x8 kbl = *(const bf16x8*)(kl + off);
                sa[kc] = __builtin_amdgcn_mfma_f32_32x32x16_bf16(qh[es], kbh, sa[kc], 0, 0, 0);
                sa[kc] = __builtin_amdgcn_mfma_f32_32x32x16_bf16(qh[es], kbl, sa[kc], 0, 0, 0);
                sa[kc] = __builtin_amdgcn_mfma_f32_32x32x16_bf16(ql[es], kbh, sa[kc], 0, 0, 0);
            }

        // ---- P = exp2(s*SCL); accumulate row sums; write swizzled LDS ----
        #pragma unroll
        for (int kc = 0; kc < 2; ++kc) {
            const int k = kc * 32 + lid;
            uint pu[16];
            #pragma unroll
            for (int r = 0; r < 16; ++r) {
                const float p = exp2f(sa[kc][r] * SCL);
                ls[r] += p;
                ushort hi, lov; split_bf16(p, hi, lov);
                pu[r] = (uint)hi | ((uint)lov << 16);
            }
            #pragma unroll
            for (int rq = 0; rq < 4; ++rq) {
                const int cq = 2 * rq + half;           // q>>2 for q=8*rq+4*half+g
                const int cs = cq ^ (k & 7);            // swizzled 16B chunk
                uint4 v = { pu[rq * 4 + 0], pu[rq * 4 + 1], pu[rq * 4 + 2], pu[rq * 4 + 3] };
                ((uint4*)Ps)[k * 8 + cs] = v;
            }
        }

        // ---- O += P V  (A = P from LDS, B = V^T from global) ----
        #pragma unroll
        for (int ks = 0; ks < 4; ++ks) {
            ushort phv[8], plv[8];
            #pragma unroll
            for (int j = 0; j < 8; ++j) {
                const int k = ks * 16 + half * 8 + j;   // k&7 == j
                const uint w = Ps[k * 32 + (((lid >> 2) ^ j) << 2) + (lid & 3)];
                phv[j] = (ushort)(w & 0xffffu);
                plv[j] = (ushort)(w >> 16);
            }
            const bf16x8 ph = *(bf16x8*)phv;
            const bf16x8 pl = *(bf16x8*)plv;
            #pragma unroll
            for (int dg = 0; dg < 2; ++dg) {
                const size_t off = kvbase + (size_t)(dg * 32 + lid) * S_LEN
                                 + kt * 64 + ks * 16 + half * 8;
                const bf16x8 vbh = *(const bf16x8*)(vth + off);
                const bf16x8 vbl = *(const bf16x8*)(vtl + off);
                o[dg] = __builtin_amdgcn_mfma_f32_32x32x16_bf16(ph, vbh, o[dg], 0, 0, 0);
                o[dg] = __builtin_amdgcn_mfma_f32_32x32x16_bf16(ph, vbl, o[dg], 0, 0, 0);
                o[dg] = __builtin_amdgcn_mfma_f32_32x32x16_bf16(pl, vbh, o[dg], 0, 0, 0);
            }
        }
    }

    // ---- row-sum reduction across the 32 key-columns (halves stay apart) ----
    #pragma unroll
    for (int r = 0; r < 16; ++r) {
        float v = ls[r];
        #pragma unroll
        for (int off = 1; off < 32; off <<= 1) v += __shfl_xor(v, off, 32);
        ls[r] = v;
    }

    // ---- epilogue: atomicAdd w_l * O / ls into ybuf[s][b][d] ----
    const int b = bh >> 4, hh = bh & 15;
    #pragma unroll
    for (int r = 0; r < 16; ++r) {
        const int q = qs0 + 8 * (r >> 2) + 4 * half + (r & 3);
        const float sc = wl / ls[r];
        #pragma unroll
        for (int dg = 0; dg < 2; ++dg) {
            const int d = hh * HDIM + dg * 32 + lid;
            atomicAdd(&yb[((size_t)q * BATCH + b) * DMODEL + d], o[dg][r] * sc);
        }
    }
}

// ---------------------------------------------------------------------------
extern "C" void kernel_launch(void* const* d_in, const int* in_sizes, int n_in,
                              void* d_out, int out_size, void* d_ws, size_t ws_size,
                              hipStream_t stream) {
    const float* x  = (const float*)d_in[0];
    const float* lo = (const float*)d_in[1];
    const float* Wq = (const float*)d_in[2];
    const float* bq = (const float*)d_in[3];
    const float* Wk = (const float*)d_in[4];
    const float* bk = (const float*)d_in[5];
    const float* Wv = (const float*)d_in[6];
    const float* bv = (const float*)d_in[7];
    const float* Wo = (const float*)d_in[8];
    const float* bo = (const float*)d_in[9];
    const float* lw = (const float*)d_in[10];
    float* out = (float*)d_out;

    char* ws = (char*)d_ws;
    float*  qbuf = (float*)(ws);                          //  8,388,608 B
    ushort* khb  = (ushort*)(ws + 8388608);               // 16,777,216 B
    ushort* klb  = (ushort*)(ws + 25165824);              // 16,777,216 B
    ushort* vthb = (ushort*)(ws + 41943040);              // 16,777,216 B
    ushort* vtlb = (ushort*)(ws + 58720256);              // 16,777,216 B
    float*  ybuf = (float*)(ws + 75497472);               //  8,388,608 B

    hipMemsetAsync(ybuf, 0, (size_t)ROWS_PL * DMODEL * sizeof(float), stream);

    dim3 blk(256);
    // Q projection (fp32 out, [bh][s][e])
    proj_mfma<1, 4, 4, 2><<<dim3(8, 32), blk, 0, stream>>>(x, lo, Wq, bq, qbuf, nullptr, nullptr, 0);
    // K projection (split bf16, [l,bh][s][e])
    proj_mfma<2, 2, 4, 4><<<dim3(8, 64), blk, 0, stream>>>(x, lo, Wk, bk, nullptr, khb, klb, 2);
    // V projection (split bf16, transposed [l,bh][e][s])
    proj_mfma<2, 2, 4, 4><<<dim3(8, 64), blk, 0, stream>>>(x, lo, Wv, bv, nullptr, vthb, vtlb, 3);
    // attention: 1 wave per (q32, bh, layer)
    attn_mfma<<<dim3(32, 32, LP1), dim3(64), 0, stream>>>(qbuf, khb, klb, vthb, vtlb, lw, ybuf);
    // output projection
    proj_mfma<1, 4, 4, 2><<<dim3(8, 32), blk, 0, stream>>>(ybuf, nullptr, Wo, bo, out, nullptr, nullptr, 1);
}

// Round 4
// 504.351 us; speedup vs baseline: 3.2063x; 1.2953x over previous
//
#include <hip/hip_runtime.h>
#include <math.h>

// Problem constants (fixed by reference setup)
#define S_LEN   1024
#define BATCH   2
#define DMODEL  1024
#define NHEADS  16
#define HDIM    64
#define BHEADS  32          // BATCH*NHEADS
#define LP1     4           // 1 + L layers
#define ROWS_PL 2048        // S*B rows per layer

typedef __attribute__((ext_vector_type(8)))  short bf16x8;   // 8 bf16 = 4 VGPRs
typedef __attribute__((ext_vector_type(4)))  float f32x4;
typedef __attribute__((ext_vector_type(16))) float f32x16;

__device__ inline ushort bf16_rne(float a) {
    unsigned u = __float_as_uint(a);
    return (ushort)((u + 0x7FFFu + ((u >> 16) & 1u)) >> 16);
}
__device__ inline float bf16_up(ushort h) { return __uint_as_float(((unsigned)h) << 16); }
__device__ inline void split_bf16(float a, ushort &hi, ushort &lo) {
    hi = bf16_rne(a);
    lo = bf16_rne(a - bf16_up(hi));
}

// ---------------------------------------------------------------------------
// Split-bf16 MFMA GEMM: C[M,N] = A[M,1024] @ W[N,1024]^T + bias[N]
// MODE 0: fp32 scatter to [l*32+b*16+h][s][e]             (Q)
// MODE 1: fp32 row-major out[m][n]                        (O-proj)
// MODE 2: split bf16 hi/lo to [l*32+b*16+h][s][e]         (K)
// MODE 3: split bf16 hi/lo to [l*32+b*16+h][e][s] via LDS transpose (V^T);
//         requires BM==BN==128. Each thread stores 128 B contiguous.
// ---------------------------------------------------------------------------
template<int WM, int WN, int MI, int NJ, int MODE>
__global__ __launch_bounds__(256)
void proj_mfma(const float* __restrict__ x, const float* __restrict__ lo,
               const float* __restrict__ W, const float* __restrict__ bias,
               float* __restrict__ outf, ushort* __restrict__ outh,
               ushort* __restrict__ outl)
{
    constexpr int BM = WM * MI * 16;
    constexpr int BN = WN * NJ * 16;
    constexpr int AT = (BM * 4) / 256;
    constexpr int BT = (BN * 4) / 256;
    constexpr int STAGE_U = (BM + BN) * 64;                 // ushorts (hi+lo planes)
    constexpr int TRANS_U = (MODE == 3) ? 128 * 130 : 0;
    constexpr int SMEM_U  = STAGE_U > TRANS_U ? STAGE_U : TRANS_U;

    __shared__ ushort smem[SMEM_U];
    ushort* Ah = smem;
    ushort* Al = Ah + BM * 32;
    ushort* Bh = Al + BM * 32;
    ushort* Bl = Bh + BN * 32;

    const int t  = threadIdx.x;
    const int m0 = blockIdx.y * BM, n0 = blockIdx.x * BN;

    const float* Abase;
    if (MODE != 1) {
        const int l = m0 >> 11;
        const float* src = (l == 0) ? x : (lo + (size_t)(l - 1) * ROWS_PL * DMODEL);
        Abase = src + (size_t)(m0 & 2047) * DMODEL;
    } else {
        Abase = x + (size_t)m0 * DMODEL;
    }
    const float* Bbase = W + (size_t)n0 * DMODEL;

    const int wave = t >> 6, lane = t & 63;
    const int quad = lane >> 4, r = lane & 15;
    const int wm = wave % WM, wn = wave / WM;
    const int mBase = wm * MI * 16, nBase = wn * NJ * 16;

    f32x4 acc[MI][NJ];
    #pragma unroll
    for (int i = 0; i < MI; ++i)
        #pragma unroll
        for (int j = 0; j < NJ; ++j) acc[i][j] = (f32x4){0.f, 0.f, 0.f, 0.f};

    for (int k0 = 0; k0 < DMODEL; k0 += 32) {
        float ar[AT][8], br[BT][8];
        #pragma unroll
        for (int c = 0; c < AT; ++c) {
            const int tau = c * 256 + t;
            const float* p = Abase + (size_t)(tau >> 2) * DMODEL + k0 + (tau & 3) * 8;
            *(float4*)&ar[c][0] = *(const float4*)p;
            *(float4*)&ar[c][4] = *(const float4*)(p + 4);
        }
        #pragma unroll
        for (int c = 0; c < BT; ++c) {
            const int tau = c * 256 + t;
            const float* p = Bbase + (size_t)(tau >> 2) * DMODEL + k0 + (tau & 3) * 8;
            *(float4*)&br[c][0] = *(const float4*)p;
            *(float4*)&br[c][4] = *(const float4*)(p + 4);
        }
        __syncthreads();
        #pragma unroll
        for (int c = 0; c < AT; ++c) {
            const int tau = c * 256 + t;
            const int row = tau >> 2, q = tau & 3;
            ushort hv[8], lv[8];
            #pragma unroll
            for (int j = 0; j < 8; ++j) split_bf16(ar[c][j], hv[j], lv[j]);
            *(uint4*)&Ah[row * 32 + q * 8] = *(uint4*)hv;
            *(uint4*)&Al[row * 32 + q * 8] = *(uint4*)lv;
        }
        #pragma unroll
        for (int c = 0; c < BT; ++c) {
            const int tau = c * 256 + t;
            const int row = tau >> 2, q = tau & 3;
            ushort hv[8], lv[8];
            #pragma unroll
            for (int j = 0; j < 8; ++j) split_bf16(br[c][j], hv[j], lv[j]);
            *(uint4*)&Bh[row * 32 + q * 8] = *(uint4*)hv;
            *(uint4*)&Bl[row * 32 + q * 8] = *(uint4*)lv;
        }
        __syncthreads();
        bf16x8 fa_h[MI], fa_l[MI], fb_h[NJ], fb_l[NJ];
        #pragma unroll
        for (int i = 0; i < MI; ++i) {
            fa_h[i] = *(const bf16x8*)&Ah[(mBase + i * 16 + r) * 32 + quad * 8];
            fa_l[i] = *(const bf16x8*)&Al[(mBase + i * 16 + r) * 32 + quad * 8];
        }
        #pragma unroll
        for (int j = 0; j < NJ; ++j) {
            fb_h[j] = *(const bf16x8*)&Bh[(nBase + j * 16 + r) * 32 + quad * 8];
            fb_l[j] = *(const bf16x8*)&Bl[(nBase + j * 16 + r) * 32 + quad * 8];
        }
        #pragma unroll
        for (int i = 0; i < MI; ++i)
            #pragma unroll
            for (int j = 0; j < NJ; ++j) {
                acc[i][j] = __builtin_amdgcn_mfma_f32_16x16x32_bf16(fa_h[i], fb_h[j], acc[i][j], 0, 0, 0);
                acc[i][j] = __builtin_amdgcn_mfma_f32_16x16x32_bf16(fa_h[i], fb_l[j], acc[i][j], 0, 0, 0);
                acc[i][j] = __builtin_amdgcn_mfma_f32_16x16x32_bf16(fa_l[i], fb_h[j], acc[i][j], 0, 0, 0);
            }
    }

    const int cn = lane & 15;

    if (MODE == 3) {
        // ---- V^T epilogue: LDS transpose, coalesced 128 B stores/thread ----
        ushort* T = smem;   // [128][130]
        __syncthreads();    // staging reads done before overwrite
        #pragma unroll
        for (int p = 0; p < 2; ++p) {
            #pragma unroll
            for (int j = 0; j < NJ; ++j) {
                const int nloc = nBase + j * 16 + cn;
                const float bv = bias[n0 + nloc];
                #pragma unroll
                for (int i = 0; i < MI; ++i) {
                    #pragma unroll
                    for (int g = 0; g < 4; ++g) {
                        const int mloc = mBase + i * 16 + quad * 4 + g;
                        ushort hi, lov; split_bf16(acc[i][j][g] + bv, hi, lov);
                        T[nloc * 130 + mloc] = p ? lov : hi;
                    }
                }
            }
            __syncthreads();
            // store: thread t -> (nloc = t>>1, b = t&1): 64 contiguous s values
            {
                const int nloc = t >> 1, bsel = t & 1;
                const int n = n0 + nloc, h = n >> 6, e = n & 63;
                const int lyr = m0 >> 11, s0g = (m0 & 2047) >> 1;
                const int bhI = lyr * 32 + bsel * 16 + h;
                ushort* plane = p ? outl : outh;
                ushort* dst = plane + ((size_t)bhI * HDIM + e) * S_LEN + s0g;
                #pragma unroll
                for (int c = 0; c < 8; ++c) {
                    ushort tmp[8];
                    #pragma unroll
                    for (int j = 0; j < 8; ++j)
                        tmp[j] = T[nloc * 130 + 2 * (c * 8 + j) + bsel];
                    *(uint4*)(dst + c * 8) = *(uint4*)tmp;
                }
            }
            __syncthreads();
        }
        return;
    }

    #pragma unroll
    for (int j = 0; j < NJ; ++j) {
        const int n = n0 + nBase + j * 16 + cn;
        const float bv = bias[n];
        #pragma unroll
        for (int i = 0; i < MI; ++i) {
            const int mrow = m0 + mBase + i * 16 + quad * 4;
            #pragma unroll
            for (int g = 0; g < 4; ++g) {
                const float val = acc[i][j][g] + bv;
                const int m = mrow + g;
                if (MODE == 1) {
                    outf[(size_t)m * DMODEL + n] = val;
                } else {
                    const int l = m >> 11, rem = m & 2047;
                    const int s = rem >> 1, b = rem & 1;
                    const int h = n >> 6, e = n & 63;
                    const int bh = l * 32 + b * 16 + h;
                    if (MODE == 0) {
                        outf[(((size_t)bh * S_LEN) + s) * HDIM + e] = val;
                    } else {   // MODE == 2 (K planes)
                        ushort hi, lov; split_bf16(val, hi, lov);
                        const size_t idx = (((size_t)bh * S_LEN) + s) * HDIM + e;
                        outh[idx] = hi; outl[idx] = lov;
                    }
                }
            }
        }
    }
}

// ---------------------------------------------------------------------------
// MFMA flash attention. Block = 256 thr = 4 waves; each wave owns q=64
// (two 32-row A-frag sets sharing every K/V fragment load -> 2x MFMA:load).
// Grid (4, 32, 4) = 512 blocks. No barriers (per-wave private LDS P tiles).
//   A-frag (32x32x16): lane holds A[m=lid][k=half*8+j]
//   C/D:               col=lid, row=(reg&3)+8*(reg>>2)+4*half
// No-max softmax (scores bounded << exp2 range), linear row sums, one
// shuffle-reduce at the end, atomicAdd epilogue into ybuf[s][b][d].
// ---------------------------------------------------------------------------
__global__ __launch_bounds__(256, 2)
void attn_mfma(const float* __restrict__ qb,
               const ushort* __restrict__ kh, const ushort* __restrict__ kl,
               const ushort* __restrict__ vth, const ushort* __restrict__ vtl,
               const float* __restrict__ lwraw, float* __restrict__ yb)
{
    __shared__ uint Ps[4][2][2048];   // [wave][qset][k*32+swz]  = 64 KB

    const int t    = threadIdx.x;
    const int wv   = t >> 6, lane = t & 63;
    const int half = lane >> 5, lid = lane & 31;
    const int bh = blockIdx.y, l = blockIdx.z;
    const int qbase = blockIdx.x * 256 + wv * 64;
    const float SCL = 0.125f * 1.44269504088896340736f;  // hd^-0.5 * log2(e)

    float wl;
    {
        float v[LP1], wm = -3.0e38f;
        #pragma unroll
        for (int i = 0; i < LP1; ++i) { v[i] = lwraw[i]; wm = fmaxf(wm, v[i]); }
        float ws = 0.f;
        #pragma unroll
        for (int i = 0; i < LP1; ++i) { v[i] = __expf(v[i] - wm); ws += v[i]; }
        wl = v[l] / ws;
    }

    // Q A-frags for both q-sets (fp32 -> split bf16 in regs), once per wave
    bf16x8 qh[2][4], ql[2][4];
    #pragma unroll
    for (int u = 0; u < 2; ++u) {
        const float* qsrc = qb + (((size_t)bh * S_LEN) + qbase + u * 32 + lid) * HDIM + half * 8;
        #pragma unroll
        for (int es = 0; es < 4; ++es) {
            float qv[8];
            *(float4*)&qv[0] = *(const float4*)(qsrc + es * 16);
            *(float4*)&qv[4] = *(const float4*)(qsrc + es * 16 + 4);
            ushort hv[8], lv[8];
            #pragma unroll
            for (int j = 0; j < 8; ++j) split_bf16(qv[j], hv[j], lv[j]);
            qh[u][es] = *(bf16x8*)hv;
            ql[u][es] = *(bf16x8*)lv;
        }
    }

    f32x16 o[2][2];
    #pragma unroll
    for (int u = 0; u < 2; ++u)
        #pragma unroll
        for (int d = 0; d < 2; ++d)
            #pragma unroll
            for (int i = 0; i < 16; ++i) o[u][d][i] = 0.f;
    float ls[2][16];
    #pragma unroll
    for (int u = 0; u < 2; ++u)
        #pragma unroll
        for (int i = 0; i < 16; ++i) ls[u][i] = 0.f;

    const size_t kvbase = (size_t)(l * BHEADS + bh) * S_LEN * HDIM;

    for (int kt = 0; kt < 16; ++kt) {
        // ---- S = Q K^T, one 32-key column at a time, both q-sets ----
        #pragma unroll
        for (int kc = 0; kc < 2; ++kc) {
            f32x16 sa[2];
            #pragma unroll
            for (int u = 0; u < 2; ++u)
                #pragma unroll
                for (int i = 0; i < 16; ++i) sa[u][i] = 0.f;

            #pragma unroll
            for (int es = 0; es < 4; ++es) {
                const size_t off = kvbase + (size_t)(kt * 64 + kc * 32 + lid) * HDIM
                                 + es * 16 + half * 8;
                const bf16x8 kbh = *(const bf16x8*)(kh + off);
                const bf16x8 kbl = *(const bf16x8*)(kl + off);
                #pragma unroll
                for (int u = 0; u < 2; ++u) {
                    sa[u] = __builtin_amdgcn_mfma_f32_32x32x16_bf16(qh[u][es], kbh, sa[u], 0, 0, 0);
                    sa[u] = __builtin_amdgcn_mfma_f32_32x32x16_bf16(qh[u][es], kbl, sa[u], 0, 0, 0);
                    sa[u] = __builtin_amdgcn_mfma_f32_32x32x16_bf16(ql[u][es], kbh, sa[u], 0, 0, 0);
                }
            }

            // P = exp2(s*SCL); row sums; swizzled per-wave LDS write
            const int k = kc * 32 + lid;
            #pragma unroll
            for (int u = 0; u < 2; ++u) {
                uint pu[16];
                #pragma unroll
                for (int r = 0; r < 16; ++r) {
                    const float p = exp2f(sa[u][r] * SCL);
                    ls[u][r] += p;
                    ushort hi, lov; split_bf16(p, hi, lov);
                    pu[r] = (uint)hi | ((uint)lov << 16);
                }
                #pragma unroll
                for (int rq = 0; rq < 4; ++rq) {
                    const int cq = 2 * rq + half;
                    const int cs = cq ^ (k & 7);
                    uint4 v = { pu[rq * 4 + 0], pu[rq * 4 + 1], pu[rq * 4 + 2], pu[rq * 4 + 3] };
                    ((uint4*)Ps[wv][u])[k * 8 + cs] = v;
                }
            }
        }

        // ---- O += P V: V frags shared across both q-sets ----
        #pragma unroll
        for (int ks = 0; ks < 4; ++ks) {
            bf16x8 vbh[2], vbl[2];
            #pragma unroll
            for (int dg = 0; dg < 2; ++dg) {
                const size_t off = kvbase + (size_t)(dg * 32 + lid) * S_LEN
                                 + kt * 64 + ks * 16 + half * 8;
                vbh[dg] = *(const bf16x8*)(vth + off);
                vbl[dg] = *(const bf16x8*)(vtl + off);
            }
            #pragma unroll
            for (int u = 0; u < 2; ++u) {
                ushort phv[8], plv[8];
                #pragma unroll
                for (int j = 0; j < 8; ++j) {
                    const int k = ks * 16 + half * 8 + j;   // k&7 == j
                    const uint w = Ps[wv][u][k * 32 + (((lid >> 2) ^ j) << 2) + (lid & 3)];
                    phv[j] = (ushort)(w & 0xffffu);
                    plv[j] = (ushort)(w >> 16);
                }
                const bf16x8 ph = *(bf16x8*)phv;
                const bf16x8 pl = *(bf16x8*)plv;
                #pragma unroll
                for (int dg = 0; dg < 2; ++dg) {
                    o[u][dg] = __builtin_amdgcn_mfma_f32_32x32x16_bf16(ph, vbh[dg], o[u][dg], 0, 0, 0);
                    o[u][dg] = __builtin_amdgcn_mfma_f32_32x32x16_bf16(ph, vbl[dg], o[u][dg], 0, 0, 0);
                    o[u][dg] = __builtin_amdgcn_mfma_f32_32x32x16_bf16(pl, vbh[dg], o[u][dg], 0, 0, 0);
                }
            }
        }
    }

    // ---- row-sum reduction across the 32 key-columns ----
    #pragma unroll
    for (int u = 0; u < 2; ++u)
        #pragma unroll
        for (int r = 0; r < 16; ++r) {
            float v = ls[u][r];
            #pragma unroll
            for (int off = 1; off < 32; off <<= 1) v += __shfl_xor(v, off, 32);
            ls[u][r] = v;
        }

    // ---- epilogue: atomicAdd w_l * O / ls into ybuf[s][b][d] ----
    const int b = bh >> 4, hh = bh & 15;
    #pragma unroll
    for (int u = 0; u < 2; ++u)
        #pragma unroll
        for (int r = 0; r < 16; ++r) {
            const int q = qbase + u * 32 + 8 * (r >> 2) + 4 * half + (r & 3);
            const float sc = wl / ls[u][r];
            #pragma unroll
            for (int dg = 0; dg < 2; ++dg) {
                const int d = hh * HDIM + dg * 32 + lid;
                atomicAdd(&yb[((size_t)q * BATCH + b) * DMODEL + d], o[u][dg][r] * sc);
            }
        }
}

// ---------------------------------------------------------------------------
extern "C" void kernel_launch(void* const* d_in, const int* in_sizes, int n_in,
                              void* d_out, int out_size, void* d_ws, size_t ws_size,
                              hipStream_t stream) {
    const float* x  = (const float*)d_in[0];
    const float* lo = (const float*)d_in[1];
    const float* Wq = (const float*)d_in[2];
    const float* bq = (const float*)d_in[3];
    const float* Wk = (const float*)d_in[4];
    const float* bk = (const float*)d_in[5];
    const float* Wv = (const float*)d_in[6];
    const float* bv = (const float*)d_in[7];
    const float* Wo = (const float*)d_in[8];
    const float* bo = (const float*)d_in[9];
    const float* lw = (const float*)d_in[10];
    float* out = (float*)d_out;

    char* ws = (char*)d_ws;
    float*  qbuf = (float*)(ws);                          //  8,388,608 B
    ushort* khb  = (ushort*)(ws + 8388608);               // 16,777,216 B
    ushort* klb  = (ushort*)(ws + 25165824);              // 16,777,216 B
    ushort* vthb = (ushort*)(ws + 41943040);              // 16,777,216 B
    ushort* vtlb = (ushort*)(ws + 58720256);              // 16,777,216 B
    float*  ybuf = (float*)(ws + 75497472);               //  8,388,608 B

    hipMemsetAsync(ybuf, 0, (size_t)ROWS_PL * DMODEL * sizeof(float), stream);

    dim3 blk(256);
    // Q projection (fp32 out, [bh][s][e])
    proj_mfma<1, 4, 4, 2, 0><<<dim3(8, 32), blk, 0, stream>>>(x, lo, Wq, bq, qbuf, nullptr, nullptr);
    // K projection (split bf16, [l,bh][s][e])
    proj_mfma<2, 2, 4, 4, 2><<<dim3(8, 64), blk, 0, stream>>>(x, lo, Wk, bk, nullptr, khb, klb);
    // V projection (split bf16, transposed [l,bh][e][s], coalesced via LDS)
    proj_mfma<2, 2, 4, 4, 3><<<dim3(8, 64), blk, 0, stream>>>(x, lo, Wv, bv, nullptr, vthb, vtlb);
    // attention: 4 waves/block, wave = q64, grid (4, 32, 4)
    attn_mfma<<<dim3(4, 32, LP1), blk, 0, stream>>>(qbuf, khb, klb, vthb, vtlb, lw, ybuf);
    // output projection
    proj_mfma<1, 4, 4, 2, 1><<<dim3(8, 32), blk, 0, stream>>>(ybuf, nullptr, Wo, bo, out, nullptr, nullptr);
}